// Round 4
// baseline (10384.634 us; speedup 1.0000x reference)
//
#include <hip/hip_runtime.h>
#include <math.h>

#define B_  2
#define T_  2048
#define C_  1024
#define NH_ 16
#define HD_ 64

// ---------------------------------------------------------------------------
// Tiled fp32 GEMM: C[MxN] = A[MxK] @ B[KxN] + bias[N]   (unchanged this round)
// ---------------------------------------------------------------------------
template<bool QKV_SCATTER>
__global__ __launch_bounds__(256)
void gemm_bias_kernel(const float* __restrict__ A, const float* __restrict__ Bm,
                      const float* __restrict__ bias, float* __restrict__ Cout,
                      int M, int N, int K,
                      float* __restrict__ q_out, float* __restrict__ k_out,
                      float* __restrict__ v_out)
{
    __shared__ float As[16][68];
    __shared__ float Bs[16][68];

    const int tid = threadIdx.x;
    const int bm = blockIdx.y * 64;
    const int bn = blockIdx.x * 64;
    const int tx = tid & 15;
    const int ty = tid >> 4;

    float acc[4][4] = {};

    for (int k0 = 0; k0 < K; k0 += 16) {
        __syncthreads();
        {
            const int l = tid * 4;
            const int r = l >> 4;
            const int c = l & 15;
            const float4 av = *reinterpret_cast<const float4*>(
                &A[(size_t)(bm + r) * K + k0 + c]);
            As[c + 0][r] = av.x;
            As[c + 1][r] = av.y;
            As[c + 2][r] = av.z;
            As[c + 3][r] = av.w;
        }
        {
            const int l = tid * 4;
            const int r = l >> 6;
            const int c = l & 63;
            const float4 bv = *reinterpret_cast<const float4*>(
                &Bm[(size_t)(k0 + r) * N + bn + c]);
            Bs[r][c + 0] = bv.x;
            Bs[r][c + 1] = bv.y;
            Bs[r][c + 2] = bv.z;
            Bs[r][c + 3] = bv.w;
        }
        __syncthreads();

        #pragma unroll
        for (int kk = 0; kk < 16; ++kk) {
            const float4 a4 = *reinterpret_cast<const float4*>(&As[kk][ty * 4]);
            const float4 b4 = *reinterpret_cast<const float4*>(&Bs[kk][tx * 4]);
            const float a[4] = {a4.x, a4.y, a4.z, a4.w};
            const float b[4] = {b4.x, b4.y, b4.z, b4.w};
            #pragma unroll
            for (int i = 0; i < 4; ++i)
                #pragma unroll
                for (int j = 0; j < 4; ++j)
                    acc[i][j] = fmaf(a[i], b[j], acc[i][j]);
        }
    }

    #pragma unroll
    for (int i = 0; i < 4; ++i) {
        const int row = bm + ty * 4 + i;
        #pragma unroll
        for (int j = 0; j < 4; ++j) {
            const int col = bn + tx * 4 + j;
            const float v = acc[i][j] + bias[col];
            if (QKV_SCATTER) {
                const int which = col >> 10;
                const int cc = col & 1023;
                const int h = cc >> 6;
                const int d = cc & 63;
                const int b = row >> 11;
                const int t = row & 2047;
                float* dst = (which == 0) ? q_out : ((which == 1) ? k_out : v_out);
                dst[(((size_t)(b * NH_ + h)) * T_ + t) * HD_ + d] = v;
            } else {
                Cout[(size_t)row * N + col] = v;
            }
        }
    }
}

// ---------------------------------------------------------------------------
// Flash-style causal attention, fp32 — latency-optimized.
// Grid: (T/64, NH, B), qt reversed (long blocks first). Block: 256 threads.
// Thread (r = tid>>2, sub = tid&3): q-row r, output dims [sub*16, sub*16+16).
// K/V double-buffered in LDS (64 KB, 2 blocks/CU), XOR-swizzled float4 layout:
//   slot(row, f) = row*16 + (f ^ ((row>>4)&3))   [float4 units]
// Register prefetch of tile kt+1 overlaps compute of kt; ONE barrier per tile.
// P kept in registers; PV pulls p via quad __shfl (no Ps LDS).
// ---------------------------------------------------------------------------
__global__ __launch_bounds__(256, 2)
void attn_kernel(const float* __restrict__ Q, const float* __restrict__ K,
                 const float* __restrict__ V, float* __restrict__ Out)
{
    __shared__ float4 KT[2][64 * 16];
    __shared__ float4 VT[2][64 * 16];

    const int tid = threadIdx.x;
    const int qt  = (T_ / 64 - 1) - blockIdx.x;   // long-running blocks first
    const int h   = blockIdx.y;
    const int b   = blockIdx.z;
    const int r   = tid >> 2;
    const int sub = tid & 3;

    const size_t bh = (size_t)(b * NH_ + h) * T_ * HD_;
    const float4* Kg = reinterpret_cast<const float4*>(K + bh);  // [T][16] f4
    const float4* Vg = reinterpret_cast<const float4*>(V + bh);

    // Q row -> registers, pre-scaled by 1/sqrt(HD)=0.125
    float4 qreg[16];
    {
        const float4* qrow = reinterpret_cast<const float4*>(
            Q + bh + (size_t)(qt * 64 + r) * HD_);
        #pragma unroll
        for (int i = 0; i < 16; ++i) {
            float4 t4 = qrow[i];
            t4.x *= 0.125f; t4.y *= 0.125f; t4.z *= 0.125f; t4.w *= 0.125f;
            qreg[i] = t4;
        }
    }

    float m = -1e30f, l = 0.f;
    float o[16] = {};

    float4 kst[4], vst[4];

    // prologue: stage tile 0 into buffer 0
    #pragma unroll
    for (int it = 0; it < 4; ++it) {
        const int e = it * 256 + tid;
        kst[it] = Kg[(size_t)(e >> 4) * 16 + (e & 15)];
        vst[it] = Vg[(size_t)(e >> 4) * 16 + (e & 15)];
    }
    #pragma unroll
    for (int it = 0; it < 4; ++it) {
        const int e = it * 256 + tid;
        const int row = e >> 4, f = e & 15;
        const int slot = row * 16 + (f ^ ((row >> 4) & 3));
        KT[0][slot] = kst[it];
        VT[0][slot] = vst[it];
    }
    __syncthreads();

    for (int kt = 0; kt <= qt; ++kt) {
        const int cur = kt & 1;

        // issue next tile's global loads early (hide latency under compute)
        if (kt < qt) {
            #pragma unroll
            for (int it = 0; it < 4; ++it) {
                const int e = it * 256 + tid;
                kst[it] = Kg[(size_t)((kt + 1) * 64 + (e >> 4)) * 16 + (e & 15)];
                vst[it] = Vg[(size_t)((kt + 1) * 64 + (e >> 4)) * 16 + (e & 15)];
            }
        }

        // scores: s[j] = q_row . K[c],  c = sub*16 + j  (swizzled reads: k4^sub)
        float s[16];
        #pragma unroll
        for (int j = 0; j < 16; ++j) {
            const int c = sub * 16 + j;
            const float4* kr = &KT[cur][c * 16];
            float acc = 0.f;
            #pragma unroll
            for (int k4 = 0; k4 < 16; ++k4) {
                const float4 kv = kr[k4 ^ sub];
                acc = fmaf(qreg[k4].x, kv.x, acc);
                acc = fmaf(qreg[k4].y, kv.y, acc);
                acc = fmaf(qreg[k4].z, kv.z, acc);
                acc = fmaf(qreg[k4].w, kv.w, acc);
            }
            s[j] = acc;
        }

        if (kt == qt) {   // diagonal tile: mask k>q
            #pragma unroll
            for (int j = 0; j < 16; ++j)
                if (sub * 16 + j > r) s[j] = -1e30f;
        }

        // online softmax (quad = 4 lanes per q-row)
        float tmax = s[0];
        #pragma unroll
        for (int j = 1; j < 16; ++j) tmax = fmaxf(tmax, s[j]);
        tmax = fmaxf(tmax, __shfl_xor(tmax, 1));
        tmax = fmaxf(tmax, __shfl_xor(tmax, 2));
        const float mnew  = fmaxf(m, tmax);
        const float alpha = __expf(m - mnew);
        float psum = 0.f;
        #pragma unroll
        for (int j = 0; j < 16; ++j) {
            s[j] = __expf(s[j] - mnew);   // s[] now holds p values
            psum += s[j];
        }
        psum += __shfl_xor(psum, 1);
        psum += __shfl_xor(psum, 2);
        l = l * alpha + psum;
        m = mnew;
        #pragma unroll
        for (int d = 0; d < 16; ++d) o[d] *= alpha;

        // PV: o[d] += sum_c p[c] * V[c][d-range];  p via quad shuffle
        {
            const float4* vb = &VT[cur][0];
            #pragma unroll
            for (int c = 0; c < 64; ++c) {
                const float p = __shfl(s[c & 15], (tid & ~3) | (c >> 4));
                const int g = (c >> 4) & 3;
                #pragma unroll
                for (int mm = 0; mm < 4; ++mm) {
                    const float4 vv = vb[c * 16 + sub * 4 + mm];
                    const int d4 = mm ^ g;   // un-swizzle: logical d-chunk
                    o[d4 * 4 + 0] = fmaf(p, vv.x, o[d4 * 4 + 0]);
                    o[d4 * 4 + 1] = fmaf(p, vv.y, o[d4 * 4 + 1]);
                    o[d4 * 4 + 2] = fmaf(p, vv.z, o[d4 * 4 + 2]);
                    o[d4 * 4 + 3] = fmaf(p, vv.w, o[d4 * 4 + 3]);
                }
            }
        }

        // write prefetched tile into the other buffer (no readers there)
        if (kt < qt) {
            #pragma unroll
            for (int it = 0; it < 4; ++it) {
                const int e = it * 256 + tid;
                const int row = e >> 4, f = e & 15;
                const int slot = row * 16 + (f ^ ((row >> 4) & 3));
                KT[cur ^ 1][slot] = kst[it];
                VT[cur ^ 1][slot] = vst[it];
            }
        }
        __syncthreads();
    }

    // normalized output -> [B*T, C] scratch (head-merged layout)
    const float inv_l = 1.0f / l;
    float* orow = Out + (size_t)(b * T_ + qt * 64 + r) * C_ + h * HD_ + sub * 16;
    #pragma unroll
    for (int d4 = 0; d4 < 4; ++d4) {
        float4 vv;
        vv.x = o[d4 * 4 + 0] * inv_l;
        vv.y = o[d4 * 4 + 1] * inv_l;
        vv.z = o[d4 * 4 + 2] * inv_l;
        vv.w = o[d4 * 4 + 3] * inv_l;
        reinterpret_cast<float4*>(orow)[d4] = vv;
    }
}

// ---------------------------------------------------------------------------
extern "C" void kernel_launch(void* const* d_in, const int* in_sizes, int n_in,
                              void* d_out, int out_size, void* d_ws, size_t ws_size,
                              hipStream_t stream) {
    const float* x      = (const float*)d_in[0];
    const float* W_qkv  = (const float*)d_in[1];
    const float* b_qkv  = (const float*)d_in[2];
    const float* W_proj = (const float*)d_in[3];
    const float* b_proj = (const float*)d_in[4];
    float* out = (float*)d_out;
    float* ws  = (float*)d_ws;

    const size_t nqkv = (size_t)B_ * NH_ * T_ * HD_;  // 4M elements
    float* qw   = ws;
    float* kw   = ws + nqkv;
    float* vw   = ws + 2 * nqkv;
    float* attn = ws + 3 * nqkv;                      // [B*T, C]

    const dim3 blk(256);

    // 1) QKV projection: [4096,1024] @ [1024,3072] + bias -> scatter to Q/K/V
    gemm_bias_kernel<true><<<dim3(3 * C_ / 64, B_ * T_ / 64), blk, 0, stream>>>(
        x, W_qkv, b_qkv, nullptr, B_ * T_, 3 * C_, C_, qw, kw, vw);

    // 2) causal flash attention -> attn [B*T, C]
    attn_kernel<<<dim3(T_ / 64, NH_, B_), blk, 0, stream>>>(qw, kw, vw, attn);

    // 3) output projection: [4096,1024] @ [1024,1024] + bias -> d_out
    gemm_bias_kernel<false><<<dim3(C_ / 64, B_ * T_ / 64), blk, 0, stream>>>(
        attn, W_proj, b_proj, out, B_ * T_, C_, C_, nullptr, nullptr, nullptr);
}

// Round 6
// 1497.074 us; speedup vs baseline: 6.9366x; 6.9366x over previous
//
#include <hip/hip_runtime.h>
#include <math.h>

#define B_  2
#define T_  2048
#define C_  1024
#define NH_ 16
#define HD_ 64

// ---------------------------------------------------------------------------
// Tiled fp32 GEMM: C[MxN] = A[MxK] @ B[KxN] + bias[N]   (unchanged this round)
// ---------------------------------------------------------------------------
template<bool QKV_SCATTER>
__global__ __launch_bounds__(256)
void gemm_bias_kernel(const float* __restrict__ A, const float* __restrict__ Bm,
                      const float* __restrict__ bias, float* __restrict__ Cout,
                      int M, int N, int K,
                      float* __restrict__ q_out, float* __restrict__ k_out,
                      float* __restrict__ v_out)
{
    __shared__ float As[16][68];
    __shared__ float Bs[16][68];

    const int tid = threadIdx.x;
    const int bm = blockIdx.y * 64;
    const int bn = blockIdx.x * 64;
    const int tx = tid & 15;
    const int ty = tid >> 4;

    float acc[4][4] = {};

    for (int k0 = 0; k0 < K; k0 += 16) {
        __syncthreads();
        {
            const int l = tid * 4;
            const int r = l >> 4;
            const int c = l & 15;
            const float4 av = *reinterpret_cast<const float4*>(
                &A[(size_t)(bm + r) * K + k0 + c]);
            As[c + 0][r] = av.x;
            As[c + 1][r] = av.y;
            As[c + 2][r] = av.z;
            As[c + 3][r] = av.w;
        }
        {
            const int l = tid * 4;
            const int r = l >> 6;
            const int c = l & 63;
            const float4 bv = *reinterpret_cast<const float4*>(
                &Bm[(size_t)(k0 + r) * N + bn + c]);
            Bs[r][c + 0] = bv.x;
            Bs[r][c + 1] = bv.y;
            Bs[r][c + 2] = bv.z;
            Bs[r][c + 3] = bv.w;
        }
        __syncthreads();

        #pragma unroll
        for (int kk = 0; kk < 16; ++kk) {
            const float4 a4 = *reinterpret_cast<const float4*>(&As[kk][ty * 4]);
            const float4 b4 = *reinterpret_cast<const float4*>(&Bs[kk][tx * 4]);
            const float a[4] = {a4.x, a4.y, a4.z, a4.w};
            const float b[4] = {b4.x, b4.y, b4.z, b4.w};
            #pragma unroll
            for (int i = 0; i < 4; ++i)
                #pragma unroll
                for (int j = 0; j < 4; ++j)
                    acc[i][j] = fmaf(a[i], b[j], acc[i][j]);
        }
    }

    #pragma unroll
    for (int i = 0; i < 4; ++i) {
        const int row = bm + ty * 4 + i;
        #pragma unroll
        for (int j = 0; j < 4; ++j) {
            const int col = bn + tx * 4 + j;
            const float v = acc[i][j] + bias[col];
            if (QKV_SCATTER) {
                const int which = col >> 10;
                const int cc = col & 1023;
                const int h = cc >> 6;
                const int d = cc & 63;
                const int b = row >> 11;
                const int t = row & 2047;
                float* dst = (which == 0) ? q_out : ((which == 1) ? k_out : v_out);
                dst[(((size_t)(b * NH_ + h)) * T_ + t) * HD_ + d] = v;
            } else {
                Cout[(size_t)row * N + col] = v;
            }
        }
    }
}

// ---------------------------------------------------------------------------
// async global->LDS, 16B per lane. LDS dest = wave-uniform base + lane*16
// (linear); swizzle is applied to the GLOBAL source address (rule #21).
// ---------------------------------------------------------------------------
__device__ __forceinline__ void gload_lds16(const void* g, void* l) {
    __builtin_amdgcn_global_load_lds(
        (const __attribute__((address_space(1))) unsigned int*)g,
        (__attribute__((address_space(3))) unsigned int*)l, 16, 0, 0);
}

// ---------------------------------------------------------------------------
// Flash-style causal attention, fp32.
// Grid: (T/64, NH, B), qt reversed (long blocks first). Block: 256 threads.
// Thread (r = tid>>2, sub = tid&3): q-row r, output dims [sub*16, sub*16+16).
// K/V double-buffered in LDS (64 KB), logical XOR-swizzled float4 layout:
//   slot(row, f_log) = row*16 + (f_log ^ ((row>>4)&3))   [float4 units]
// realized by inverse-swizzling the global SOURCE address of global_load_lds
// (XOR is an involution) while the LDS destination stays linear.
// Prefetch of tile kt+1 issued before compute of kt; ONE barrier per k-tile
// (the barrier's implicit vmcnt(0) drain completes the prefetch).
// P stays in registers; PV pulls p via quad __shfl (no Ps LDS, no spills).
// ---------------------------------------------------------------------------
__global__ __launch_bounds__(256)
void attn_kernel(const float* __restrict__ Q, const float* __restrict__ K,
                 const float* __restrict__ V, float* __restrict__ Out)
{
    __shared__ float4 KT[2][64 * 16];
    __shared__ float4 VT[2][64 * 16];

    const int tid = threadIdx.x;
    const int qt  = (T_ / 64 - 1) - blockIdx.x;   // long-running blocks first
    const int h   = blockIdx.y;
    const int b   = blockIdx.z;
    const int r   = tid >> 2;
    const int sub = tid & 3;

    const size_t bh = (size_t)(b * NH_ + h) * T_ * HD_;
    const float4* Kg = reinterpret_cast<const float4*>(K + bh);  // [T][16] f4
    const float4* Vg = reinterpret_cast<const float4*>(V + bh);

    // stage tile kt into buffer buf: 8 async 16B loads per thread
    auto stage_tile = [&](int buf, int kt) {
        #pragma unroll
        for (int it = 0; it < 4; ++it) {
            const int e   = it * 256 + tid;       // linear LDS slot (float4)
            const int row = e >> 4, f = e & 15;
            const int g   = (row >> 4) & 3;
            const size_t gidx = (size_t)(kt * 64 + row) * 16 + (f ^ g);
            const int ldsbase = it * 256 + (tid & ~63);   // wave-uniform
            gload_lds16(&Kg[gidx], &KT[buf][ldsbase]);
            gload_lds16(&Vg[gidx], &VT[buf][ldsbase]);
        }
    };

    // Q row -> registers, pre-scaled by 1/sqrt(HD)=0.125
    float4 qreg[16];
    {
        const float4* qrow = reinterpret_cast<const float4*>(
            Q + bh + (size_t)(qt * 64 + r) * HD_);
        #pragma unroll
        for (int i = 0; i < 16; ++i) {
            float4 t4 = qrow[i];
            t4.x *= 0.125f; t4.y *= 0.125f; t4.z *= 0.125f; t4.w *= 0.125f;
            qreg[i] = t4;
        }
    }

    float m = -1e30f, l = 0.f;
    float o[16] = {};

    // prologue: stage tile 0 into buffer 0
    stage_tile(0, 0);
    __syncthreads();   // implicit vmcnt(0) drain -> tile 0 resident

    for (int kt = 0; kt <= qt; ++kt) {
        const int cur = kt & 1;

        // issue next tile's async loads into the other buffer
        if (kt < qt) stage_tile(cur ^ 1, kt + 1);

        // scores: s[j] = q_row . K[c],  c = sub*16 + j  (swizzled reads: k4^sub)
        float s[16];
        #pragma unroll
        for (int j = 0; j < 16; ++j) {
            const int c = sub * 16 + j;
            const float4* kr = &KT[cur][c * 16];
            float acc = 0.f;
            #pragma unroll
            for (int k4 = 0; k4 < 16; ++k4) {
                const float4 kv = kr[k4 ^ sub];
                acc = fmaf(qreg[k4].x, kv.x, acc);
                acc = fmaf(qreg[k4].y, kv.y, acc);
                acc = fmaf(qreg[k4].z, kv.z, acc);
                acc = fmaf(qreg[k4].w, kv.w, acc);
            }
            s[j] = acc;
        }

        if (kt == qt) {   // diagonal tile: mask k>q
            #pragma unroll
            for (int j = 0; j < 16; ++j)
                if (sub * 16 + j > r) s[j] = -1e30f;
        }

        // online softmax (quad = 4 lanes per q-row)
        float tmax = s[0];
        #pragma unroll
        for (int j = 1; j < 16; ++j) tmax = fmaxf(tmax, s[j]);
        tmax = fmaxf(tmax, __shfl_xor(tmax, 1));
        tmax = fmaxf(tmax, __shfl_xor(tmax, 2));
        const float mnew  = fmaxf(m, tmax);
        const float alpha = __expf(m - mnew);
        float psum = 0.f;
        #pragma unroll
        for (int j = 0; j < 16; ++j) {
            s[j] = __expf(s[j] - mnew);   // s[] now holds p values
            psum += s[j];
        }
        psum += __shfl_xor(psum, 1);
        psum += __shfl_xor(psum, 2);
        l = l * alpha + psum;
        m = mnew;
        #pragma unroll
        for (int d = 0; d < 16; ++d) o[d] *= alpha;

        // PV: o[d] += sum_c p[c] * V[c][d-range];  p via quad shuffle
        {
            const float4* vb = &VT[cur][0];
            #pragma unroll
            for (int c = 0; c < 64; ++c) {
                const float p = __shfl(s[c & 15], (tid & ~3) | (c >> 4));
                const int g = (c >> 4) & 3;
                #pragma unroll
                for (int mm = 0; mm < 4; ++mm) {
                    const float4 vv = vb[c * 16 + sub * 4 + mm];
                    const int d4 = mm ^ g;   // un-swizzle: logical d-chunk
                    o[d4 * 4 + 0] = fmaf(p, vv.x, o[d4 * 4 + 0]);
                    o[d4 * 4 + 1] = fmaf(p, vv.y, o[d4 * 4 + 1]);
                    o[d4 * 4 + 2] = fmaf(p, vv.z, o[d4 * 4 + 2]);
                    o[d4 * 4 + 3] = fmaf(p, vv.w, o[d4 * 4 + 3]);
                }
            }
        }

        // barrier: all waves done reading buf cur; implicit vmcnt(0) drain
        // completes the prefetch into buf cur^1
        __syncthreads();
    }

    // normalized output -> [B*T, C] scratch (head-merged layout)
    const float inv_l = 1.0f / l;
    float* orow = Out + (size_t)(b * T_ + qt * 64 + r) * C_ + h * HD_ + sub * 16;
    #pragma unroll
    for (int d4 = 0; d4 < 4; ++d4) {
        float4 vv;
        vv.x = o[d4 * 4 + 0] * inv_l;
        vv.y = o[d4 * 4 + 1] * inv_l;
        vv.z = o[d4 * 4 + 2] * inv_l;
        vv.w = o[d4 * 4 + 3] * inv_l;
        reinterpret_cast<float4*>(orow)[d4] = vv;
    }
}

// ---------------------------------------------------------------------------
extern "C" void kernel_launch(void* const* d_in, const int* in_sizes, int n_in,
                              void* d_out, int out_size, void* d_ws, size_t ws_size,
                              hipStream_t stream) {
    const float* x      = (const float*)d_in[0];
    const float* W_qkv  = (const float*)d_in[1];
    const float* b_qkv  = (const float*)d_in[2];
    const float* W_proj = (const float*)d_in[3];
    const float* b_proj = (const float*)d_in[4];
    float* out = (float*)d_out;
    float* ws  = (float*)d_ws;

    const size_t nqkv = (size_t)B_ * NH_ * T_ * HD_;  // 4M elements
    float* qw   = ws;
    float* kw   = ws + nqkv;
    float* vw   = ws + 2 * nqkv;
    float* attn = ws + 3 * nqkv;                      // [B*T, C]

    const dim3 blk(256);

    // 1) QKV projection: [4096,1024] @ [1024,3072] + bias -> scatter to Q/K/V
    gemm_bias_kernel<true><<<dim3(3 * C_ / 64, B_ * T_ / 64), blk, 0, stream>>>(
        x, W_qkv, b_qkv, nullptr, B_ * T_, 3 * C_, C_, qw, kw, vw);

    // 2) causal flash attention -> attn [B*T, C]
    attn_kernel<<<dim3(T_ / 64, NH_, B_), blk, 0, stream>>>(qw, kw, vw, attn);

    // 3) output projection: [4096,1024] @ [1024,1024] + bias -> d_out
    gemm_bias_kernel<false><<<dim3(C_ / 64, B_ * T_ / 64), blk, 0, stream>>>(
        attn, W_proj, b_proj, out, B_ * T_, C_, C_, nullptr, nullptr, nullptr);
}

// Round 8
// 630.975 us; speedup vs baseline: 16.4581x; 2.3726x over previous
//
#include <hip/hip_runtime.h>
#include <math.h>

#define B_  2
#define T_  2048
#define C_  1024
#define NH_ 16
#define HD_ 64

typedef short bf16x8 __attribute__((ext_vector_type(8)));
typedef float f32x4  __attribute__((ext_vector_type(4)));

__device__ __forceinline__ unsigned short f2bf(float f) {
    unsigned u = __builtin_bit_cast(unsigned, f);
    u += 0x7fffu + ((u >> 16) & 1u);          // round-to-nearest-even
    return (unsigned short)(u >> 16);
}

// ---------------------------------------------------------------------------
// Tiled fp32 GEMM: C[MxN] = A[MxK] @ B[KxN] + bias[N].
// QKV_SCATTER epilogue: Q (x0.125) and K -> [B,NH,T,HD] bf16;
//                       V -> [B,NH,HD,T] bf16 (transposed for PV B-operand).
// ---------------------------------------------------------------------------
template<bool QKV_SCATTER>
__global__ __launch_bounds__(256)
void gemm_bias_kernel(const float* __restrict__ A, const float* __restrict__ Bm,
                      const float* __restrict__ bias, float* __restrict__ Cout,
                      int M, int N, int K,
                      unsigned short* __restrict__ q_out,
                      unsigned short* __restrict__ k_out,
                      unsigned short* __restrict__ v_out)
{
    __shared__ float As[16][68];
    __shared__ float Bs[16][68];

    const int tid = threadIdx.x;
    const int bm = blockIdx.y * 64;
    const int bn = blockIdx.x * 64;
    const int tx = tid & 15;
    const int ty = tid >> 4;

    float acc[4][4] = {};

    for (int k0 = 0; k0 < K; k0 += 16) {
        __syncthreads();
        {
            const int l = tid * 4;
            const int r = l >> 4;
            const int c = l & 15;
            const float4 av = *reinterpret_cast<const float4*>(
                &A[(size_t)(bm + r) * K + k0 + c]);
            As[c + 0][r] = av.x;
            As[c + 1][r] = av.y;
            As[c + 2][r] = av.z;
            As[c + 3][r] = av.w;
        }
        {
            const int l = tid * 4;
            const int r = l >> 6;
            const int c = l & 63;
            const float4 bv = *reinterpret_cast<const float4*>(
                &Bm[(size_t)(k0 + r) * N + bn + c]);
            Bs[r][c + 0] = bv.x;
            Bs[r][c + 1] = bv.y;
            Bs[r][c + 2] = bv.z;
            Bs[r][c + 3] = bv.w;
        }
        __syncthreads();

        #pragma unroll
        for (int kk = 0; kk < 16; ++kk) {
            const float4 a4 = *reinterpret_cast<const float4*>(&As[kk][ty * 4]);
            const float4 b4 = *reinterpret_cast<const float4*>(&Bs[kk][tx * 4]);
            const float a[4] = {a4.x, a4.y, a4.z, a4.w};
            const float b[4] = {b4.x, b4.y, b4.z, b4.w};
            #pragma unroll
            for (int i = 0; i < 4; ++i)
                #pragma unroll
                for (int j = 0; j < 4; ++j)
                    acc[i][j] = fmaf(a[i], b[j], acc[i][j]);
        }
    }

    #pragma unroll
    for (int i = 0; i < 4; ++i) {
        const int row = bm + ty * 4 + i;
        #pragma unroll
        for (int j = 0; j < 4; ++j) {
            const int col = bn + tx * 4 + j;
            const float v = acc[i][j] + bias[col];
            if (QKV_SCATTER) {
                const int which = col >> 10;     // 0=q 1=k 2=v
                const int cc = col & 1023;
                const int h = cc >> 6;
                const int d = cc & 63;
                const int b = row >> 11;
                const int t = row & 2047;
                const size_t bhh = (size_t)(b * NH_ + h);
                if (which == 0)
                    q_out[(bhh * T_ + t) * HD_ + d] = f2bf(v * 0.125f);
                else if (which == 1)
                    k_out[(bhh * T_ + t) * HD_ + d] = f2bf(v);
                else
                    v_out[(bhh * HD_ + d) * T_ + t] = f2bf(v);   // transposed
            } else {
                Cout[(size_t)row * N + col] = v;
            }
        }
    }
}

// ---------------------------------------------------------------------------
__device__ __forceinline__ void gload_lds16(const void* g, void* l) {
    __builtin_amdgcn_global_load_lds(
        (const __attribute__((address_space(1))) unsigned int*)g,
        (__attribute__((address_space(3))) unsigned int*)l, 16, 0, 0);
}

// ---------------------------------------------------------------------------
// MFMA causal flash attention (bf16 in, fp32 accum).
// Grid (T/64, NH, B) qt-reversed; 256 thr = 4 waves; wave w owns q-rows
// [qt*64+w*16, +16). KVBLK=64. All LDS tiles are [64 rows][64 bf16] = 128B
// rows, 8x16B slots, swizzle slot^=(row&7) applied on the global SOURCE of
// global_load_lds (LDS dest linear) and on every frag read (rule #21).
// S^T = mfma(K, Q) so col=q -> softmax is lane-local + shfl_xor(16,32).
// P (bf16) -> per-wave LDS -> A-operand of PV; V stored transposed globally.
// ---------------------------------------------------------------------------
__global__ __launch_bounds__(256)
void attn_kernel(const unsigned short* __restrict__ Q,
                 const unsigned short* __restrict__ K,
                 const unsigned short* __restrict__ Vt,
                 float* __restrict__ Out)
{
    __shared__ __align__(16) unsigned char Qs[8192];
    __shared__ __align__(16) unsigned char Ks[2][8192];
    __shared__ __align__(16) unsigned char Vs[2][8192];
    __shared__ __align__(16) unsigned char Ps[4][2048];

    const int tid  = threadIdx.x;
    const int w    = tid >> 6;          // wave 0..3
    const int lane = tid & 63;
    const int c    = lane & 15;         // MFMA col index
    const int g    = lane >> 4;         // lane group 0..3
    const int qt   = (T_ / 64 - 1) - blockIdx.x;
    const int h    = blockIdx.y;
    const int b    = blockIdx.z;

    const size_t bh = (size_t)(b * NH_ + h) * T_ * HD_;
    const unsigned short* Qg = Q + bh;
    const unsigned short* Kg = K + bh;
    const unsigned short* Vg = Vt + bh;          // [HD][T] per (b,h)

    // stage one 64x64 bf16 tile of K and Vt (8 KB each) into buffer buf
    auto stage_kv = [&](int buf, int kt) {
        #pragma unroll
        for (int it = 0; it < 2; ++it) {
            const int chunk = it * 256 + tid;     // 0..511 (16B units)
            const int row = chunk >> 3, s = chunk & 7;
            const int ss = s ^ (row & 7);         // pre-swizzled source slot
            gload_lds16(Kg + (size_t)(kt * 64 + row) * HD_ + ss * 8,
                        (char*)Ks[buf] + it * 4096 + (tid & ~63) * 16);
            gload_lds16(Vg + (size_t)row * T_ + kt * 64 + ss * 8,
                        (char*)Vs[buf] + it * 4096 + (tid & ~63) * 16);
        }
    };

    // swizzled fragment read: 8 bf16 at (row, 16B-slot)
    auto ldfrag = [&](const unsigned char* base, int row, int slot) -> bf16x8 {
        return *reinterpret_cast<const bf16x8*>(
            base + row * 128 + ((slot ^ (row & 7)) * 16));
    };

    // prologue: Q tile (once) + K/V tile 0
    #pragma unroll
    for (int it = 0; it < 2; ++it) {
        const int chunk = it * 256 + tid;
        const int row = chunk >> 3, s = chunk & 7;
        const int ss = s ^ (row & 7);
        gload_lds16(Qg + (size_t)(qt * 64 + row) * HD_ + ss * 8,
                    (char*)Qs + it * 4096 + (tid & ~63) * 16);
    }
    stage_kv(0, 0);
    __syncthreads();

    float mcol = -1e30f, lcol = 0.f;   // per q-column state (col = c)
    f32x4 Oacc[4] = {};                // 4 d-tiles; row = 4*g+reg, col = c

    for (int kt = 0; kt <= qt; ++kt) {
        const int cur = kt & 1;
        if (kt < qt) stage_kv(cur ^ 1, kt + 1);

        // S^T[key][q]: A=K rows (t*16+c), B=Q^T (col=q=c)
        bf16x8 qf[2];
        #pragma unroll
        for (int ks = 0; ks < 2; ++ks)
            qf[ks] = ldfrag(Qs, w * 16 + c, ks * 4 + g);

        f32x4 Sacc[4] = {};
        #pragma unroll
        for (int t = 0; t < 4; ++t)
            #pragma unroll
            for (int ks = 0; ks < 2; ++ks) {
                const bf16x8 kf = ldfrag(Ks[cur], t * 16 + c, ks * 4 + g);
                Sacc[t] = __builtin_amdgcn_mfma_f32_16x16x32_bf16(
                    kf, qf[ks], Sacc[t], 0, 0, 0);
            }

        if (kt == qt) {   // diagonal: mask key_local > q_local
            const int q_l = w * 16 + c;
            #pragma unroll
            for (int t = 0; t < 4; ++t)
                #pragma unroll
                for (int r2 = 0; r2 < 4; ++r2)
                    if (t * 16 + g * 4 + r2 > q_l) Sacc[t][r2] = -1e30f;
        }

        // online softmax over column q=c (16 lane-local + xor 16,32)
        float tmax = -1e30f;
        #pragma unroll
        for (int t = 0; t < 4; ++t)
            #pragma unroll
            for (int r2 = 0; r2 < 4; ++r2) tmax = fmaxf(tmax, Sacc[t][r2]);
        tmax = fmaxf(tmax, __shfl_xor(tmax, 16));
        tmax = fmaxf(tmax, __shfl_xor(tmax, 32));
        const float mnew  = fmaxf(mcol, tmax);
        const float alpha = __expf(mcol - mnew);
        mcol = mnew;

        float psum = 0.f;
        unsigned pk[4][2];
        #pragma unroll
        for (int t = 0; t < 4; ++t) {
            const float p0 = __expf(Sacc[t][0] - mnew);
            const float p1 = __expf(Sacc[t][1] - mnew);
            const float p2 = __expf(Sacc[t][2] - mnew);
            const float p3 = __expf(Sacc[t][3] - mnew);
            psum += (p0 + p1) + (p2 + p3);
            pk[t][0] = (unsigned)f2bf(p0) | ((unsigned)f2bf(p1) << 16);
            pk[t][1] = (unsigned)f2bf(p2) | ((unsigned)f2bf(p3) << 16);
        }
        psum += __shfl_xor(psum, 16);
        psum += __shfl_xor(psum, 32);
        lcol = lcol * alpha + psum;

        // P -> per-wave LDS [16 q rows][64 keys] bf16, same swizzle scheme
        {
            unsigned char* pbase = Ps[w];
            #pragma unroll
            for (int t = 0; t < 4; ++t)
                #pragma unroll
                for (int rp = 0; rp < 2; ++rp) {
                    const int off = (32 * t + 8 * g + 4 * rp) ^ ((c & 7) << 4);
                    *reinterpret_cast<unsigned*>(pbase + c * 128 + off) = pk[t][rp];
                }
        }

        // rescale O rows (row q = 4g+reg; alpha lives at lanes with c == q)
        #pragma unroll
        for (int r2 = 0; r2 < 4; ++r2) {
            const float av = __shfl(alpha, g * 20 + r2);
            #pragma unroll
            for (int dt = 0; dt < 4; ++dt) Oacc[dt][r2] *= av;
        }

        // ensure P writes visible to all lanes of this wave before frag reads
        asm volatile("s_waitcnt lgkmcnt(0)" ::: "memory");
        __builtin_amdgcn_sched_barrier(0);

        // PV: A = P[q][key] (row=c), B = Vt[d][key] (col=d=dt*16+c)
        bf16x8 pf[2];
        #pragma unroll
        for (int ks = 0; ks < 2; ++ks)
            pf[ks] = ldfrag(Ps[w], c, ks * 4 + g);
        #pragma unroll
        for (int dt = 0; dt < 4; ++dt)
            #pragma unroll
            for (int ks = 0; ks < 2; ++ks) {
                const bf16x8 vf = ldfrag(Vs[cur], dt * 16 + c, ks * 4 + g);
                Oacc[dt] = __builtin_amdgcn_mfma_f32_16x16x32_bf16(
                    pf[ks], vf, Oacc[dt], 0, 0, 0);
            }

        // all waves done with buf cur; barrier drains prefetch (vmcnt(0))
        __syncthreads();
    }

    // epilogue: normalize, write fp32 [B*T, C] head-merged scratch
    const float invl = 1.0f / lcol;
    #pragma unroll
    for (int r2 = 0; r2 < 4; ++r2) {
        const float il = __shfl(invl, g * 20 + r2);
        const int qgl = qt * 64 + w * 16 + g * 4 + r2;
        float* orow = Out + (size_t)(b * T_ + qgl) * C_ + h * HD_;
        #pragma unroll
        for (int dt = 0; dt < 4; ++dt)
            orow[dt * 16 + c] = Oacc[dt][r2] * il;
    }
}

// ---------------------------------------------------------------------------
extern "C" void kernel_launch(void* const* d_in, const int* in_sizes, int n_in,
                              void* d_out, int out_size, void* d_ws, size_t ws_size,
                              hipStream_t stream) {
    const float* x      = (const float*)d_in[0];
    const float* W_qkv  = (const float*)d_in[1];
    const float* b_qkv  = (const float*)d_in[2];
    const float* W_proj = (const float*)d_in[3];
    const float* b_proj = (const float*)d_in[4];
    float* out = (float*)d_out;

    const size_t nqkv = (size_t)B_ * NH_ * T_ * HD_;   // 4M elements
    unsigned short* qw = (unsigned short*)d_ws;        // bf16 [B,NH,T,HD]
    unsigned short* kw = qw + nqkv;                    // bf16 [B,NH,T,HD]
    unsigned short* vw = kw + nqkv;                    // bf16 [B,NH,HD,T]
    float* attn = (float*)(vw + nqkv);                 // fp32 [B*T, C]

    const dim3 blk(256);

    // 1) QKV projection + bias -> bf16 Q/K (Q pre-scaled), V transposed
    gemm_bias_kernel<true><<<dim3(3 * C_ / 64, B_ * T_ / 64), blk, 0, stream>>>(
        x, W_qkv, b_qkv, nullptr, B_ * T_, 3 * C_, C_, qw, kw, vw);

    // 2) causal MFMA flash attention -> attn [B*T, C] fp32
    attn_kernel<<<dim3(T_ / 64, NH_, B_), blk, 0, stream>>>(qw, kw, vw, attn);

    // 3) output projection: [4096,1024] @ [1024,1024] + bias -> d_out
    gemm_bias_kernel<false><<<dim3(C_ / 64, B_ * T_ / 64), blk, 0, stream>>>(
        attn, W_proj, b_proj, out, B_ * T_, C_, C_, nullptr, nullptr, nullptr);
}

// Round 9
// 277.407 us; speedup vs baseline: 37.4347x; 2.2745x over previous
//
#include <hip/hip_runtime.h>
#include <math.h>

#define B_  2
#define T_  2048
#define C_  1024
#define NH_ 16
#define HD_ 64

typedef _Float16 half8  __attribute__((ext_vector_type(8)));
typedef _Float16 half4v __attribute__((ext_vector_type(4)));
typedef float    f32x4  __attribute__((ext_vector_type(4)));

__device__ __forceinline__ unsigned short f2h(float f) {
    _Float16 h = (_Float16)f;
    return __builtin_bit_cast(unsigned short, h);
}

// ---------------------------------------------------------------------------
__device__ __forceinline__ void gload_lds16(const void* g, void* l) {
    __builtin_amdgcn_global_load_lds(
        (const __attribute__((address_space(1))) unsigned int*)g,
        (__attribute__((address_space(3))) unsigned int*)l, 16, 0, 0);
}

// ---------------------------------------------------------------------------
// x [4096][1024] fp32 -> fp16, row-major (A-operand layout). 8 elems/thread.
// ---------------------------------------------------------------------------
__global__ __launch_bounds__(256)
void convert_x(const float* __restrict__ x, _Float16* __restrict__ xh, int n8)
{
    const int i = blockIdx.x * 256 + threadIdx.x;
    if (i < n8) {
        const float4 a = reinterpret_cast<const float4*>(x)[2 * i];
        const float4 b = reinterpret_cast<const float4*>(x)[2 * i + 1];
        half8 o;
        o[0] = (_Float16)a.x; o[1] = (_Float16)a.y;
        o[2] = (_Float16)a.z; o[3] = (_Float16)a.w;
        o[4] = (_Float16)b.x; o[5] = (_Float16)b.y;
        o[6] = (_Float16)b.z; o[7] = (_Float16)b.w;
        *reinterpret_cast<half8*>(&xh[(size_t)i * 8]) = o;
    }
}

// ---------------------------------------------------------------------------
// W [K][N] fp32 -> Wt [N][K] fp16 (transposed, B^T layout). 64x64 LDS tiles.
// ---------------------------------------------------------------------------
__global__ __launch_bounds__(256)
void convert_wt(const float* __restrict__ W, _Float16* __restrict__ Wt,
                int K, int N)
{
    __shared__ float t[64][65];
    const int tid = threadIdx.x;
    const int n0 = blockIdx.x * 64, k0 = blockIdx.y * 64;

    for (int i = tid; i < 64 * 16; i += 256) {
        const int r = i >> 4, c4 = (i & 15) * 4;
        const float4 v = *reinterpret_cast<const float4*>(
            &W[(size_t)(k0 + r) * N + n0 + c4]);
        t[r][c4 + 0] = v.x; t[r][c4 + 1] = v.y;
        t[r][c4 + 2] = v.z; t[r][c4 + 3] = v.w;
    }
    __syncthreads();
    for (int i = tid; i < 64 * 16; i += 256) {
        const int r = i >> 4, c4 = (i & 15) * 4;   // r = n-local, c4 = k-local
        half4v o;
        o[0] = (_Float16)t[c4 + 0][r];
        o[1] = (_Float16)t[c4 + 1][r];
        o[2] = (_Float16)t[c4 + 2][r];
        o[3] = (_Float16)t[c4 + 3][r];
        *reinterpret_cast<half4v*>(&Wt[(size_t)(n0 + r) * K + k0 + c4]) = o;
    }
}

// ---------------------------------------------------------------------------
// fp16 MFMA GEMM: C[M,N] = A[M,K] @ Bt[N,K]^T + bias.  128x128 tile, BK=32,
// 256 thr = 4 waves, each 64x64 (4x4 frags of 16x16x32). LDS is k-chunk-major
// in 16B units: idx = kc*128 + row  (kc = k/8) -> frag reads lane-contiguous,
// conflict-free, no swizzle. global_load_lds(16B) staging, double-buffered,
// one barrier per K-step (its vmcnt(0) drain completes the prefetch).
// QKV_SCATTER epilogue: q (x0.125), k -> [B,NH,T,HD] fp16; v -> [B,NH,HD,T].
// ---------------------------------------------------------------------------
template<bool QKV_SCATTER>
__global__ __launch_bounds__(256)
void gemm_mfma(const _Float16* __restrict__ A, const _Float16* __restrict__ Bt,
               const float* __restrict__ bias, float* __restrict__ Cout,
               int M, int N, int K,
               _Float16* __restrict__ qh, _Float16* __restrict__ kh,
               _Float16* __restrict__ vh)
{
    __shared__ __align__(16) _Float16 Asl[2][128 * 32];
    __shared__ __align__(16) _Float16 Bsl[2][128 * 32];

    const int tid  = threadIdx.x;
    const int w    = tid >> 6;
    const int lane = tid & 63;
    const int c    = lane & 15;      // frag row/col index
    const int g    = lane >> 4;      // k-chunk group
    const int wr   = w >> 1, wc = w & 1;
    const int bm   = blockIdx.y * 128, bn = blockIdx.x * 128;

    f32x4 acc[4][4] = {};

    auto stage = [&](int buf, int k0) {
        #pragma unroll
        for (int it = 0; it < 2; ++it) {
            const int e   = it * 256 + tid;       // 0..511 (16B units)
            const int row = e & 127, kc = e >> 7;
            const char* ldsA = (const char*)&Asl[buf][0];
            const char* ldsB = (const char*)&Bsl[buf][0];
            const int dst = (it * 256 + (tid & ~63)) * 16;   // wave-uniform
            gload_lds16(A  + (size_t)(bm + row) * K + k0 + kc * 8, (void*)(ldsA + dst));
            gload_lds16(Bt + (size_t)(bn + row) * K + k0 + kc * 8, (void*)(ldsB + dst));
        }
    };

    stage(0, 0);
    __syncthreads();

    for (int k0 = 0, it = 0; k0 < K; k0 += 32, ++it) {
        const int cur = it & 1;
        if (k0 + 32 < K) stage(cur ^ 1, k0 + 32);

        half8 af[4], bf[4];
        #pragma unroll
        for (int i = 0; i < 4; ++i) {
            const int row = wr * 64 + i * 16 + c;
            af[i] = *reinterpret_cast<const half8*>(
                (const char*)&Asl[cur][0] + (g * 128 + row) * 16);
        }
        #pragma unroll
        for (int j = 0; j < 4; ++j) {
            const int row = wc * 64 + j * 16 + c;
            bf[j] = *reinterpret_cast<const half8*>(
                (const char*)&Bsl[cur][0] + (g * 128 + row) * 16);
        }
        #pragma unroll
        for (int i = 0; i < 4; ++i)
            #pragma unroll
            for (int j = 0; j < 4; ++j)
                acc[i][j] = __builtin_amdgcn_mfma_f32_16x16x32_f16(
                    af[i], bf[j], acc[i][j], 0, 0, 0);

        __syncthreads();   // waves done with cur; prefetch into cur^1 drained
    }

    // epilogue: C/D layout col=lane&15, row=(lane>>4)*4+reg
    #pragma unroll
    for (int i = 0; i < 4; ++i) {
        const int row0 = bm + wr * 64 + i * 16 + g * 4;
        #pragma unroll
        for (int j = 0; j < 4; ++j) {
            const int col = bn + wc * 64 + j * 16 + c;
            const float bv = bias[col];
            #pragma unroll
            for (int r2 = 0; r2 < 4; ++r2) {
                const float v = acc[i][j][r2] + bv;
                const int rr = row0 + r2;
                if (QKV_SCATTER) {
                    const int which = col >> 10;     // 0=q 1=k 2=v
                    const int cc = col & 1023;
                    const int hh = cc >> 6;
                    const int d  = cc & 63;
                    const int bb = rr >> 11;
                    const int t  = rr & 2047;
                    const size_t bhh = (size_t)(bb * NH_ + hh);
                    if (which == 0)
                        qh[(bhh * T_ + t) * HD_ + d] = (_Float16)(v * 0.125f);
                    else if (which == 1)
                        kh[(bhh * T_ + t) * HD_ + d] = (_Float16)v;
                    else
                        vh[(bhh * HD_ + d) * T_ + t] = (_Float16)v;
                } else {
                    Cout[(size_t)rr * N + col] = v;
                }
            }
        }
    }
}

// ---------------------------------------------------------------------------
// MFMA causal flash attention (fp16 in, fp32 accum) — structure identical to
// the round-8 bf16 version (passed on HW), dtype swapped.
// ---------------------------------------------------------------------------
__global__ __launch_bounds__(256)
void attn_kernel(const _Float16* __restrict__ Q,
                 const _Float16* __restrict__ K,
                 const _Float16* __restrict__ Vt,
                 _Float16* __restrict__ Out)
{
    __shared__ __align__(16) unsigned char Qs[8192];
    __shared__ __align__(16) unsigned char Ks[2][8192];
    __shared__ __align__(16) unsigned char Vs[2][8192];
    __shared__ __align__(16) unsigned char Ps[4][2048];

    const int tid  = threadIdx.x;
    const int w    = tid >> 6;
    const int lane = tid & 63;
    const int c    = lane & 15;
    const int g    = lane >> 4;
    const int qt   = (T_ / 64 - 1) - blockIdx.x;
    const int h    = blockIdx.y;
    const int b    = blockIdx.z;

    const size_t bh = (size_t)(b * NH_ + h) * T_ * HD_;
    const _Float16* Qg = Q + bh;
    const _Float16* Kg = K + bh;
    const _Float16* Vg = Vt + bh;               // [HD][T] per (b,h)

    auto stage_kv = [&](int buf, int kt) {
        #pragma unroll
        for (int it = 0; it < 2; ++it) {
            const int chunk = it * 256 + tid;
            const int row = chunk >> 3, s = chunk & 7;
            const int ss = s ^ (row & 7);
            gload_lds16(Kg + (size_t)(kt * 64 + row) * HD_ + ss * 8,
                        (char*)Ks[buf] + it * 4096 + (tid & ~63) * 16);
            gload_lds16(Vg + (size_t)row * T_ + kt * 64 + ss * 8,
                        (char*)Vs[buf] + it * 4096 + (tid & ~63) * 16);
        }
    };

    auto ldfrag = [&](const unsigned char* base, int row, int slot) -> half8 {
        return *reinterpret_cast<const half8*>(
            base + row * 128 + ((slot ^ (row & 7)) * 16));
    };

    #pragma unroll
    for (int it = 0; it < 2; ++it) {
        const int chunk = it * 256 + tid;
        const int row = chunk >> 3, s = chunk & 7;
        const int ss = s ^ (row & 7);
        gload_lds16(Qg + (size_t)(qt * 64 + row) * HD_ + ss * 8,
                    (char*)Qs + it * 4096 + (tid & ~63) * 16);
    }
    stage_kv(0, 0);
    __syncthreads();

    float mcol = -1e30f, lcol = 0.f;
    f32x4 Oacc[4] = {};

    for (int kt = 0; kt <= qt; ++kt) {
        const int cur = kt & 1;
        if (kt < qt) stage_kv(cur ^ 1, kt + 1);

        half8 qf[2];
        #pragma unroll
        for (int ks = 0; ks < 2; ++ks)
            qf[ks] = ldfrag(Qs, w * 16 + c, ks * 4 + g);

        f32x4 Sacc[4] = {};
        #pragma unroll
        for (int t = 0; t < 4; ++t)
            #pragma unroll
            for (int ks = 0; ks < 2; ++ks) {
                const half8 kf = ldfrag(Ks[cur], t * 16 + c, ks * 4 + g);
                Sacc[t] = __builtin_amdgcn_mfma_f32_16x16x32_f16(
                    kf, qf[ks], Sacc[t], 0, 0, 0);
            }

        if (kt == qt) {
            const int q_l = w * 16 + c;
            #pragma unroll
            for (int t = 0; t < 4; ++t)
                #pragma unroll
                for (int r2 = 0; r2 < 4; ++r2)
                    if (t * 16 + g * 4 + r2 > q_l) Sacc[t][r2] = -1e30f;
        }

        float tmax = -1e30f;
        #pragma unroll
        for (int t = 0; t < 4; ++t)
            #pragma unroll
            for (int r2 = 0; r2 < 4; ++r2) tmax = fmaxf(tmax, Sacc[t][r2]);
        tmax = fmaxf(tmax, __shfl_xor(tmax, 16));
        tmax = fmaxf(tmax, __shfl_xor(tmax, 32));
        const float mnew  = fmaxf(mcol, tmax);
        const float alpha = __expf(mcol - mnew);
        mcol = mnew;

        float psum = 0.f;
        unsigned pk[4][2];
        #pragma unroll
        for (int t = 0; t < 4; ++t) {
            const float p0 = __expf(Sacc[t][0] - mnew);
            const float p1 = __expf(Sacc[t][1] - mnew);
            const float p2 = __expf(Sacc[t][2] - mnew);
            const float p3 = __expf(Sacc[t][3] - mnew);
            psum += (p0 + p1) + (p2 + p3);
            pk[t][0] = (unsigned)f2h(p0) | ((unsigned)f2h(p1) << 16);
            pk[t][1] = (unsigned)f2h(p2) | ((unsigned)f2h(p3) << 16);
        }
        psum += __shfl_xor(psum, 16);
        psum += __shfl_xor(psum, 32);
        lcol = lcol * alpha + psum;

        {
            unsigned char* pbase = Ps[w];
            #pragma unroll
            for (int t = 0; t < 4; ++t)
                #pragma unroll
                for (int rp = 0; rp < 2; ++rp) {
                    const int off = (32 * t + 8 * g + 4 * rp) ^ ((c & 7) << 4);
                    *reinterpret_cast<unsigned*>(pbase + c * 128 + off) = pk[t][rp];
                }
        }

        #pragma unroll
        for (int r2 = 0; r2 < 4; ++r2) {
            const float av = __shfl(alpha, g * 20 + r2);
            #pragma unroll
            for (int dt = 0; dt < 4; ++dt) Oacc[dt][r2] *= av;
        }

        asm volatile("s_waitcnt lgkmcnt(0)" ::: "memory");
        __builtin_amdgcn_sched_barrier(0);

        half8 pf[2];
        #pragma unroll
        for (int ks = 0; ks < 2; ++ks)
            pf[ks] = ldfrag(Ps[w], c, ks * 4 + g);
        #pragma unroll
        for (int dt = 0; dt < 4; ++dt)
            #pragma unroll
            for (int ks = 0; ks < 2; ++ks) {
                const half8 vf = ldfrag(Vs[cur], dt * 16 + c, ks * 4 + g);
                Oacc[dt] = __builtin_amdgcn_mfma_f32_16x16x32_f16(
                    pf[ks], vf, Oacc[dt], 0, 0, 0);
            }

        __syncthreads();
    }

    const float invl = 1.0f / lcol;
    #pragma unroll
    for (int r2 = 0; r2 < 4; ++r2) {
        const float il = __shfl(invl, g * 20 + r2);
        const int qgl = qt * 64 + w * 16 + g * 4 + r2;
        _Float16* orow = Out + (size_t)(b * T_ + qgl) * C_ + h * HD_;
        #pragma unroll
        for (int dt = 0; dt < 4; ++dt)
            orow[dt * 16 + c] = (_Float16)(Oacc[dt][r2] * il);
    }
}

// ---------------------------------------------------------------------------
extern "C" void kernel_launch(void* const* d_in, const int* in_sizes, int n_in,
                              void* d_out, int out_size, void* d_ws, size_t ws_size,
                              hipStream_t stream) {
    const float* x      = (const float*)d_in[0];
    const float* W_qkv  = (const float*)d_in[1];
    const float* b_qkv  = (const float*)d_in[2];
    const float* W_proj = (const float*)d_in[3];
    const float* b_proj = (const float*)d_in[4];
    float* out = (float*)d_out;

    const size_t M4 = (size_t)B_ * T_ * C_;            // 4M
    _Float16* xh  = (_Float16*)d_ws;                   // [4096][1024]
    _Float16* wqt = xh  + M4;                          // [3072][1024] (B^T)
    _Float16* wpt = wqt + 3 * C_ * C_;                 // [1024][1024] (B^T)
    _Float16* qh  = wpt + (size_t)C_ * C_;             // [B,NH,T,HD]
    _Float16* kh  = qh  + M4;                          // [B,NH,T,HD]
    _Float16* vh  = kh  + M4;                          // [B,NH,HD,T]
    _Float16* ah  = vh  + M4;                          // [B*T][C]

    const dim3 blk(256);

    // 0) conversions
    convert_x<<<dim3((B_ * T_ * C_ / 8 + 255) / 256), blk, 0, stream>>>(
        x, xh, B_ * T_ * C_ / 8);
    convert_wt<<<dim3(3 * C_ / 64, C_ / 64), blk, 0, stream>>>(
        W_qkv, wqt, C_, 3 * C_);
    convert_wt<<<dim3(C_ / 64, C_ / 64), blk, 0, stream>>>(
        W_proj, wpt, C_, C_);

    // 1) QKV projection (fp16 MFMA) + bias -> q (x0.125), k, v^T fp16
    gemm_mfma<true><<<dim3(3 * C_ / 128, B_ * T_ / 128), blk, 0, stream>>>(
        xh, wqt, b_qkv, nullptr, B_ * T_, 3 * C_, C_, qh, kh, vh);

    // 2) causal MFMA flash attention -> ah fp16 [B*T, C]
    attn_kernel<<<dim3(T_ / 64, NH_, B_), blk, 0, stream>>>(qh, kh, vh, ah);

    // 3) output projection (fp16 MFMA) + bias -> d_out fp32
    gemm_mfma<false><<<dim3(C_ / 128, B_ * T_ / 128), blk, 0, stream>>>(
        ah, wpt, b_proj, out, B_ * T_, C_, C_, nullptr, nullptr, nullptr);
}

// Round 13
// 239.544 us; speedup vs baseline: 43.3518x; 1.1581x over previous
//
#include <hip/hip_runtime.h>
#include <math.h>

#define B_  2
#define T_  2048
#define C_  1024
#define NH_ 16
#define HD_ 64

typedef _Float16 half8  __attribute__((ext_vector_type(8)));
typedef _Float16 half4v __attribute__((ext_vector_type(4)));
typedef float    f32x4  __attribute__((ext_vector_type(4)));

__device__ __forceinline__ unsigned short f2h(float f) {
    _Float16 h = (_Float16)f;
    return __builtin_bit_cast(unsigned short, h);
}

// ---------------------------------------------------------------------------
__device__ __forceinline__ void gload_lds16(const void* g, void* l) {
    __builtin_amdgcn_global_load_lds(
        (const __attribute__((address_space(1))) unsigned int*)g,
        (__attribute__((address_space(3))) unsigned int*)l, 16, 0, 0);
}

// ---------------------------------------------------------------------------
// x [4096][1024] fp32 -> fp16, row-major. 8 elems/thread.
// ---------------------------------------------------------------------------
__global__ __launch_bounds__(256)
void convert_x(const float* __restrict__ x, _Float16* __restrict__ xh, int n8)
{
    const int i = blockIdx.x * 256 + threadIdx.x;
    if (i < n8) {
        const float4 a = reinterpret_cast<const float4*>(x)[2 * i];
        const float4 b = reinterpret_cast<const float4*>(x)[2 * i + 1];
        half8 o;
        o[0] = (_Float16)a.x; o[1] = (_Float16)a.y;
        o[2] = (_Float16)a.z; o[3] = (_Float16)a.w;
        o[4] = (_Float16)b.x; o[5] = (_Float16)b.y;
        o[6] = (_Float16)b.z; o[7] = (_Float16)b.w;
        *reinterpret_cast<half8*>(&xh[(size_t)i * 8]) = o;
    }
}

// ---------------------------------------------------------------------------
// W [K][N] fp32 -> Wt [N][K] fp16 (transposed, B^T layout). 64x64 LDS tiles.
// ---------------------------------------------------------------------------
__global__ __launch_bounds__(256)
void convert_wt(const float* __restrict__ W, _Float16* __restrict__ Wt,
                int K, int N)
{
    __shared__ float t[64][65];
    const int tid = threadIdx.x;
    const int n0 = blockIdx.x * 64, k0 = blockIdx.y * 64;

    for (int i = tid; i < 64 * 16; i += 256) {
        const int r = i >> 4, c4 = (i & 15) * 4;
        const float4 v = *reinterpret_cast<const float4*>(
            &W[(size_t)(k0 + r) * N + n0 + c4]);
        t[r][c4 + 0] = v.x; t[r][c4 + 1] = v.y;
        t[r][c4 + 2] = v.z; t[r][c4 + 3] = v.w;
    }
    __syncthreads();
    for (int i = tid; i < 64 * 16; i += 256) {
        const int r = i >> 4, c4 = (i & 15) * 4;   // r = n-local, c4 = k-local
        half4v o;
        o[0] = (_Float16)t[c4 + 0][r];
        o[1] = (_Float16)t[c4 + 1][r];
        o[2] = (_Float16)t[c4 + 2][r];
        o[3] = (_Float16)t[c4 + 3][r];
        *reinterpret_cast<half4v*>(&Wt[(size_t)(n0 + r) * K + k0 + c4]) = o;
    }
}

// ---------------------------------------------------------------------------
// fp16 MFMA GEMM (HW-verified round 9).
// ---------------------------------------------------------------------------
template<bool QKV_SCATTER>
__global__ __launch_bounds__(256)
void gemm_mfma(const _Float16* __restrict__ A, const _Float16* __restrict__ Bt,
               const float* __restrict__ bias, float* __restrict__ Cout,
               int M, int N, int K,
               _Float16* __restrict__ qh, _Float16* __restrict__ kh,
               _Float16* __restrict__ vh)
{
    __shared__ __align__(16) _Float16 Asl[2][128 * 32];
    __shared__ __align__(16) _Float16 Bsl[2][128 * 32];

    const int tid  = threadIdx.x;
    const int w    = tid >> 6;
    const int lane = tid & 63;
    const int c    = lane & 15;
    const int g    = lane >> 4;
    const int wr   = w >> 1, wc = w & 1;
    const int bm   = blockIdx.y * 128, bn = blockIdx.x * 128;

    f32x4 acc[4][4] = {};

    auto stage = [&](int buf, int k0) {
        #pragma unroll
        for (int it = 0; it < 2; ++it) {
            const int e   = it * 256 + tid;
            const int row = e & 127, kc = e >> 7;
            const char* ldsA = (const char*)&Asl[buf][0];
            const char* ldsB = (const char*)&Bsl[buf][0];
            const int dst = (it * 256 + (tid & ~63)) * 16;
            gload_lds16(A  + (size_t)(bm + row) * K + k0 + kc * 8, (void*)(ldsA + dst));
            gload_lds16(Bt + (size_t)(bn + row) * K + k0 + kc * 8, (void*)(ldsB + dst));
        }
    };

    stage(0, 0);
    __syncthreads();

    for (int k0 = 0, it = 0; k0 < K; k0 += 32, ++it) {
        const int cur = it & 1;
        if (k0 + 32 < K) stage(cur ^ 1, k0 + 32);

        half8 af[4], bf[4];
        #pragma unroll
        for (int i = 0; i < 4; ++i) {
            const int row = wr * 64 + i * 16 + c;
            af[i] = *reinterpret_cast<const half8*>(
                (const char*)&Asl[cur][0] + (g * 128 + row) * 16);
        }
        #pragma unroll
        for (int j = 0; j < 4; ++j) {
            const int row = wc * 64 + j * 16 + c;
            bf[j] = *reinterpret_cast<const half8*>(
                (const char*)&Bsl[cur][0] + (g * 128 + row) * 16);
        }
        #pragma unroll
        for (int i = 0; i < 4; ++i)
            #pragma unroll
            for (int j = 0; j < 4; ++j)
                acc[i][j] = __builtin_amdgcn_mfma_f32_16x16x32_f16(
                    af[i], bf[j], acc[i][j], 0, 0, 0);

        __syncthreads();
    }

    #pragma unroll
    for (int i = 0; i < 4; ++i) {
        const int row0 = bm + wr * 64 + i * 16 + g * 4;
        #pragma unroll
        for (int j = 0; j < 4; ++j) {
            const int col = bn + wc * 64 + j * 16 + c;
            const float bv = bias[col];
            #pragma unroll
            for (int r2 = 0; r2 < 4; ++r2) {
                const float v = acc[i][j][r2] + bv;
                const int rr = row0 + r2;
                if (QKV_SCATTER) {
                    const int which = col >> 10;
                    const int cc = col & 1023;
                    const int hh = cc >> 6;
                    const int d  = cc & 63;
                    const int bb = rr >> 11;
                    const int t  = rr & 2047;
                    const size_t bhh = (size_t)(bb * NH_ + hh);
                    if (which == 0)
                        qh[(bhh * T_ + t) * HD_ + d] = (_Float16)(v * 0.125f);
                    else if (which == 1)
                        kh[(bhh * T_ + t) * HD_ + d] = (_Float16)v;
                    else
                        vh[(bhh * HD_ + d) * T_ + t] = (_Float16)v;
                } else {
                    Cout[(size_t)rr * N + col] = v;
                }
            }
        }
    }
}

// ---------------------------------------------------------------------------
// MFMA causal flash attention, fp16, 2 q-tiles per block (qa=p, qb=31-p).
// Work per block is UNIFORM: (qa+1)+(qb+1) = 33 tile-units for every p.
// Grid (T/128, NH, B) = 512 blocks, LDS 64KB -> 2 blocks/CU (exact fill).
// Two independent softmax chains per wave -> ILP hides the serial chain.
// Q fragments hoisted to registers (read once). Layouts identical to the
// HW-verified round-9 kernel.
// ---------------------------------------------------------------------------
__global__ __launch_bounds__(256)
void attn_kernel(const _Float16* __restrict__ Q,
                 const _Float16* __restrict__ K,
                 const _Float16* __restrict__ Vt,
                 _Float16* __restrict__ Out)
{
    __shared__ __align__(16) unsigned char Qs[16384];    // [2 tiles][64][64]
    __shared__ __align__(16) unsigned char Ks[2][8192];
    __shared__ __align__(16) unsigned char Vs[2][8192];
    __shared__ __align__(16) unsigned char Psa[4][2048];
    __shared__ __align__(16) unsigned char Psb[4][2048];

    const int tid  = threadIdx.x;
    const int w    = tid >> 6;
    const int lane = tid & 63;
    const int c    = lane & 15;
    const int g    = lane >> 4;
    const int p    = blockIdx.x;               // 0..15
    const int qa   = p;
    const int qb   = (T_ / 64 - 1) - p;        // 31-p
    const int h    = blockIdx.y;
    const int b    = blockIdx.z;

    const size_t bh = (size_t)(b * NH_ + h) * T_ * HD_;
    const _Float16* Qg = Q + bh;
    const _Float16* Kg = K + bh;
    const _Float16* Vg = Vt + bh;              // [HD][T] per (b,h)

    auto stage_kv = [&](int buf, int kt) {
        #pragma unroll
        for (int it = 0; it < 2; ++it) {
            const int chunk = it * 256 + tid;
            const int row = chunk >> 3, s = chunk & 7;
            const int ss = s ^ (row & 7);
            gload_lds16(Kg + (size_t)(kt * 64 + row) * HD_ + ss * 8,
                        (char*)Ks[buf] + it * 4096 + (tid & ~63) * 16);
            gload_lds16(Vg + (size_t)row * T_ + kt * 64 + ss * 8,
                        (char*)Vs[buf] + it * 4096 + (tid & ~63) * 16);
        }
    };

    auto ldfrag = [&](const unsigned char* base, int row, int slot) -> half8 {
        return *reinterpret_cast<const half8*>(
            base + row * 128 + ((slot ^ (row & 7)) * 16));
    };

    // prologue: stage both Q tiles (a -> rows 0..63, b -> rows 64..127)
    #pragma unroll
    for (int it = 0; it < 4; ++it) {
        const int chunk = it * 256 + tid;          // 0..1023 16B units
        const int row = chunk >> 3, s = chunk & 7; // row 0..127
        const int ss = s ^ (row & 7);
        const int qrow = (row < 64) ? (qa * 64 + row) : (qb * 64 + row - 64);
        gload_lds16(Qg + (size_t)qrow * HD_ + ss * 8,
                    (char*)Qs + it * 4096 + (tid & ~63) * 16);
    }
    stage_kv(0, 0);
    __syncthreads();

    // hoist Q fragments (reused every iteration)
    half8 qfa[2], qfb[2];
    #pragma unroll
    for (int ks = 0; ks < 2; ++ks) {
        qfa[ks] = ldfrag(Qs, w * 16 + c, ks * 4 + g);
        qfb[ks] = ldfrag(Qs + 8192, w * 16 + c, ks * 4 + g);
    }

    float ma = -1e30f, la = 0.f, mb = -1e30f, lb = 0.f;
    f32x4 Oa[4] = {}, Ob[4] = {};

    for (int kt = 0; kt <= qb; ++kt) {
        const int cur = kt & 1;
        if (kt < qb) stage_kv(cur ^ 1, kt + 1);
        const bool doA = (kt <= qa);

        // ---- QK^T for b (always) and a (when active); independent chains
        f32x4 Sb[4] = {};
        #pragma unroll
        for (int t = 0; t < 4; ++t)
            #pragma unroll
            for (int ks = 0; ks < 2; ++ks) {
                const half8 kf = ldfrag(Ks[cur], t * 16 + c, ks * 4 + g);
                Sb[t] = __builtin_amdgcn_mfma_f32_16x16x32_f16(
                    kf, qfb[ks], Sb[t], 0, 0, 0);
            }
        f32x4 Sa[4] = {};
        if (doA) {
            #pragma unroll
            for (int t = 0; t < 4; ++t)
                #pragma unroll
                for (int ks = 0; ks < 2; ++ks) {
                    const half8 kf = ldfrag(Ks[cur], t * 16 + c, ks * 4 + g);
                    Sa[t] = __builtin_amdgcn_mfma_f32_16x16x32_f16(
                        kf, qfa[ks], Sa[t], 0, 0, 0);
                }
        }

        // ---- masks (diagonal tiles)
        if (kt == qb) {
            const int q_l = w * 16 + c;
            #pragma unroll
            for (int t = 0; t < 4; ++t)
                #pragma unroll
                for (int r2 = 0; r2 < 4; ++r2)
                    if (t * 16 + g * 4 + r2 > q_l) Sb[t][r2] = -1e30f;
        }
        if (doA && kt == qa) {
            const int q_l = w * 16 + c;
            #pragma unroll
            for (int t = 0; t < 4; ++t)
                #pragma unroll
                for (int r2 = 0; r2 < 4; ++r2)
                    if (t * 16 + g * 4 + r2 > q_l) Sa[t][r2] = -1e30f;
        }

        // ---- online softmax b  (chain 1)
        float tb = -1e30f;
        #pragma unroll
        for (int t = 0; t < 4; ++t)
            #pragma unroll
            for (int r2 = 0; r2 < 4; ++r2) tb = fmaxf(tb, Sb[t][r2]);
        tb = fmaxf(tb, __shfl_xor(tb, 16));
        tb = fmaxf(tb, __shfl_xor(tb, 32));
        const float mnb = fmaxf(mb, tb);
        const float alb = __expf(mb - mnb);
        mb = mnb;
        float psb = 0.f;
        unsigned pkb[4][2];
        #pragma unroll
        for (int t = 0; t < 4; ++t) {
            const float p0 = __expf(Sb[t][0] - mnb);
            const float p1 = __expf(Sb[t][1] - mnb);
            const float p2 = __expf(Sb[t][2] - mnb);
            const float p3 = __expf(Sb[t][3] - mnb);
            psb += (p0 + p1) + (p2 + p3);
            pkb[t][0] = (unsigned)f2h(p0) | ((unsigned)f2h(p1) << 16);
            pkb[t][1] = (unsigned)f2h(p2) | ((unsigned)f2h(p3) << 16);
        }
        psb += __shfl_xor(psb, 16);
        psb += __shfl_xor(psb, 32);
        lb = lb * alb + psb;
        {
            unsigned char* pb = Psb[w];
            #pragma unroll
            for (int t = 0; t < 4; ++t)
                #pragma unroll
                for (int rp = 0; rp < 2; ++rp) {
                    const int off = (32 * t + 8 * g + 4 * rp) ^ ((c & 7) << 4);
                    *reinterpret_cast<unsigned*>(pb + c * 128 + off) = pkb[t][rp];
                }
        }
        #pragma unroll
        for (int r2 = 0; r2 < 4; ++r2) {
            const float av = __shfl(alb, g * 20 + r2);
            #pragma unroll
            for (int dt = 0; dt < 4; ++dt) Ob[dt][r2] *= av;
        }

        // ---- online softmax a  (chain 2, independent)
        if (doA) {
            float ta = -1e30f;
            #pragma unroll
            for (int t = 0; t < 4; ++t)
                #pragma unroll
                for (int r2 = 0; r2 < 4; ++r2) ta = fmaxf(ta, Sa[t][r2]);
            ta = fmaxf(ta, __shfl_xor(ta, 16));
            ta = fmaxf(ta, __shfl_xor(ta, 32));
            const float mna = fmaxf(ma, ta);
            const float ala = __expf(ma - mna);
            ma = mna;
            float psa = 0.f;
            unsigned pka[4][2];
            #pragma unroll
            for (int t = 0; t < 4; ++t) {
                const float p0 = __expf(Sa[t][0] - mna);
                const float p1 = __expf(Sa[t][1] - mna);
                const float p2 = __expf(Sa[t][2] - mna);
                const float p3 = __expf(Sa[t][3] - mna);
                psa += (p0 + p1) + (p2 + p3);
                pka[t][0] = (unsigned)f2h(p0) | ((unsigned)f2h(p1) << 16);
                pka[t][1] = (unsigned)f2h(p2) | ((unsigned)f2h(p3) << 16);
            }
            psa += __shfl_xor(psa, 16);
            psa += __shfl_xor(psa, 32);
            la = la * ala + psa;
            unsigned char* pa = Psa[w];
            #pragma unroll
            for (int t = 0; t < 4; ++t)
                #pragma unroll
                for (int rp = 0; rp < 2; ++rp) {
                    const int off = (32 * t + 8 * g + 4 * rp) ^ ((c & 7) << 4);
                    *reinterpret_cast<unsigned*>(pa + c * 128 + off) = pka[t][rp];
                }
            #pragma unroll
            for (int r2 = 0; r2 < 4; ++r2) {
                const float av = __shfl(ala, g * 20 + r2);
                #pragma unroll
                for (int dt = 0; dt < 4; ++dt) Oa[dt][r2] *= av;
            }
        }

        // P writes visible to this wave's lanes before frag reads
        asm volatile("s_waitcnt lgkmcnt(0)" ::: "memory");
        __builtin_amdgcn_sched_barrier(0);

        // ---- PV for b and a
        {
            half8 pf[2];
            #pragma unroll
            for (int ks = 0; ks < 2; ++ks)
                pf[ks] = ldfrag(Psb[w], c, ks * 4 + g);
            #pragma unroll
            for (int dt = 0; dt < 4; ++dt)
                #pragma unroll
                for (int ks = 0; ks < 2; ++ks) {
                    const half8 vf = ldfrag(Vs[cur], dt * 16 + c, ks * 4 + g);
                    Ob[dt] = __builtin_amdgcn_mfma_f32_16x16x32_f16(
                        pf[ks], vf, Ob[dt], 0, 0, 0);
                }
        }
        if (doA) {
            half8 pf[2];
            #pragma unroll
            for (int ks = 0; ks < 2; ++ks)
                pf[ks] = ldfrag(Psa[w], c, ks * 4 + g);
            #pragma unroll
            for (int dt = 0; dt < 4; ++dt)
                #pragma unroll
                for (int ks = 0; ks < 2; ++ks) {
                    const half8 vf = ldfrag(Vs[cur], dt * 16 + c, ks * 4 + g);
                    Oa[dt] = __builtin_amdgcn_mfma_f32_16x16x32_f16(
                        pf[ks], vf, Oa[dt], 0, 0, 0);
                }
        }

        __syncthreads();   // waves done with buf cur; prefetch drained
    }

    // epilogue: both q-tiles
    {
        const float il0 = 1.0f / lb;
        #pragma unroll
        for (int r2 = 0; r2 < 4; ++r2) {
            const float il = __shfl(il0, g * 20 + r2);
            const int qgl = qb * 64 + w * 16 + g * 4 + r2;
            _Float16* orow = Out + (size_t)(b * T_ + qgl) * C_ + h * HD_;
            #pragma unroll
            for (int dt = 0; dt < 4; ++dt)
                orow[dt * 16 + c] = (_Float16)(Ob[dt][r2] * il);
        }
    }
    {
        const float il0 = 1.0f / la;
        #pragma unroll
        for (int r2 = 0; r2 < 4; ++r2) {
            const float il = __shfl(il0, g * 20 + r2);
            const int qgl = qa * 64 + w * 16 + g * 4 + r2;
            _Float16* orow = Out + (size_t)(b * T_ + qgl) * C_ + h * HD_;
            #pragma unroll
            for (int dt = 0; dt < 4; ++dt)
                orow[dt * 16 + c] = (_Float16)(Oa[dt][r2] * il);
        }
    }
}

// ---------------------------------------------------------------------------
extern "C" void kernel_launch(void* const* d_in, const int* in_sizes, int n_in,
                              void* d_out, int out_size, void* d_ws, size_t ws_size,
                              hipStream_t stream) {
    const float* x      = (const float*)d_in[0];
    const float* W_qkv  = (const float*)d_in[1];
    const float* b_qkv  = (const float*)d_in[2];
    const float* W_proj = (const float*)d_in[3];
    const float* b_proj = (const float*)d_in[4];
    float* out = (float*)d_out;

    const size_t M4 = (size_t)B_ * T_ * C_;            // 4M
    _Float16* xh  = (_Float16*)d_ws;                   // [4096][1024]
    _Float16* wqt = xh  + M4;                          // [3072][1024] (B^T)
    _Float16* wpt = wqt + 3 * C_ * C_;                 // [1024][1024] (B^T)
    _Float16* qh  = wpt + (size_t)C_ * C_;             // [B,NH,T,HD]
    _Float16* kh  = qh  + M4;                          // [B,NH,T,HD]
    _Float16* vh  = kh  + M4;                          // [B,NH,HD,T]
    _Float16* ah  = vh  + M4;                          // [B*T][C]

    const dim3 blk(256);

    // 0) conversions
    convert_x<<<dim3((B_ * T_ * C_ / 8 + 255) / 256), blk, 0, stream>>>(
        x, xh, B_ * T_ * C_ / 8);
    convert_wt<<<dim3(3 * C_ / 64, C_ / 64), blk, 0, stream>>>(
        W_qkv, wqt, C_, 3 * C_);
    convert_wt<<<dim3(C_ / 64, C_ / 64), blk, 0, stream>>>(
        W_proj, wpt, C_, C_);

    // 1) QKV projection (fp16 MFMA) + bias -> q (x0.125), k, v^T fp16
    gemm_mfma<true><<<dim3(3 * C_ / 128, B_ * T_ / 128), blk, 0, stream>>>(
        xh, wqt, b_qkv, nullptr, B_ * T_, 3 * C_, C_, qh, kh, vh);

    // 2) causal MFMA flash attention (2 q-tiles/block) -> ah fp16 [B*T, C]
    attn_kernel<<<dim3(T_ / 128, NH_, B_), blk, 0, stream>>>(qh, kh, vh, ah);

    // 3) output projection (fp16 MFMA) + bias -> d_out fp32
    gemm_mfma<false><<<dim3(C_ / 128, B_ * T_ / 128), blk, 0, stream>>>(
        ah, wpt, b_proj, out, B_ * T_, C_, C_, nullptr, nullptr, nullptr);
}